// Round 3
// baseline (275.670 us; speedup 1.0000x reference)
//
#include <hip/hip_runtime.h>

// PositionWiseSpatialAttention — fused flash-style kernel, MI355X gfx950.
//
// R8: barrier-free main loop.
//  - presplit (R7, unchanged): x -> {hi,lo} bf16, row-major + transposed,
//    plus theta^T, in workspace. Staging math done once.
//  - spattn3: 128-row blocks, 4 waves x 32 rows (R5 compute structure).
//    K and V MFMA B-fragments are b128-loaded DIRECTLY from the pre-split
//    workspace (L1/L2-hot; K/V per g = 512 KB, L2-fits) — no K/V LDS, no
//    loop barriers. R7 was LDS-throughput-bound (~310 LDS-cyc/wave-tile,
//    17.4M bank conflicts); LDS now carries only the wave-private P
//    round-trip. XCD-aware swizzle keeps each g's 8 row-blocks on one XCD
//    (R7's fetch blow-up: bx%8 spread each g over all 8 XCDs' L2s).
// Math identical to R7 (same split data, scale folded into exp2) ->
// absmax unchanged.

#define NB    8
#define NT    12
#define NNODE 1024
#define ND    64
#define XROW  768   /* NT*ND: stride between consecutive n for fixed (b,t) */
#define NG    96    /* NB*NT */

typedef __bf16 bf16x8 __attribute__((ext_vector_type(8)));
typedef __bf16 bf16x4 __attribute__((ext_vector_type(4)));
typedef float  floatx4 __attribute__((ext_vector_type(4)));

#define MFMA(a,b,c) __builtin_amdgcn_mfma_f32_16x16x32_bf16((a),(b),(c),0,0,0)

#define QSCALE 0.18033688011112042f   /* 0.125 * log2(e) */

// LDS: wave-private P plus epilogue AG overlay (no K/V staging anymore).
#define PSTRIDE 36   /* f32 per P row: 144 B */
#define AGSTRIDE 68  /* f32 per AG row (epilogue overlay) */
#define SMEM3 (128 * AGSTRIDE * 4)        /* 34816 >= 128*PSTRIDE*4 */
#define SMEM_FB (19456 + 128*PSTRIDE*4)   /* fallback (R5): 37888 */

// fallback LDS map (R5)
#define KSTRIDE 72
#define VSTRIDE 40
#define OFF_KHI 0
#define OFF_KLO 4608
#define OFF_VHI 9216
#define OFF_VLO 14336
#define OFF_P   19456

// workspace element offsets (__bf16 units)
#define WXHI  0          /* [96][1024][64] row-major hi  */
#define WXLO  6291456
#define WXTHI 12582912   /* [96][64][1024] transposed hi */
#define WXTLO 18874368
#define WTHI  25165824   /* [64 o][64 d] theta^T hi      */
#define WTLO  25169920
#define WS_BYTES 50348032ULL

struct bfpair { __bf16 h, l; };

// error-compensated split: hi = RNE(f) via native fptrunc, lo = RNE(f - hi).
// |f - hi - lo| ~ 2^-17 |f|.
__device__ __forceinline__ bfpair split1(float f) {
    bfpair r;
    __bf16 hb = (__bf16)f;
    float hf = __builtin_bit_cast(float,
                   (unsigned)__builtin_bit_cast(unsigned short, hb) << 16);
    r.h = hb;
    r.l = (__bf16)(f - hf);
    return r;
}

// ---------------------------------------------------------------------------
// presplit: grid 1536 (96 g x 16 n-blocks), 256 threads. (R7, verified)
// ---------------------------------------------------------------------------
__global__ void __launch_bounds__(256)
presplit(const float* __restrict__ x, const float* __restrict__ theta,
         __bf16* __restrict__ ws)
{
    __shared__ __align__(16) float T[64 * 68];
    const int tid  = threadIdx.x;
    const int bx   = blockIdx.x;
    const int g    = bx >> 4;
    const int nblk = bx & 15;
    const int bb   = g / NT;
    const int tt   = g - bb * NT;
    const int n0   = nblk * 64;

    __bf16* Xhi  = ws + WXHI  + (size_t)g * 65536;
    __bf16* Xlo  = ws + WXLO  + (size_t)g * 65536;
    __bf16* XThi = ws + WXTHI + (size_t)g * 65536;
    __bf16* XTlo = ws + WXTLO + (size_t)g * 65536;
    const float* xg = x + (size_t)bb * (NNODE * XROW) + (size_t)tt * ND;

    #pragma unroll
    for (int i = 0; i < 4; ++i) {
        int chunk = i * 256 + tid;        // 0..1023
        int n  = chunk >> 4;              // 0..63
        int c4 = (chunk & 15) * 4;        // 0..60
        floatx4 f = *(const floatx4*)(xg + (size_t)(n0 + n) * XROW + c4);
        *(floatx4*)(T + n * 68 + c4) = f;
        bf16x4 h, l;
        #pragma unroll
        for (int j = 0; j < 4; ++j) {
            bfpair p = split1(f[j]); h[j] = p.h; l[j] = p.l;
        }
        *(bf16x4*)(Xhi + (size_t)(n0 + n) * 64 + c4) = h;
        *(bf16x4*)(Xlo + (size_t)(n0 + n) * 64 + c4) = l;
    }
    __syncthreads();

    {
        const int d  = tid >> 2;          // 0..63
        const int nc = (tid & 3) * 16;    // 0..48
        bf16x8 h0, l0, h1, l1;
        #pragma unroll
        for (int j = 0; j < 8; ++j) {
            bfpair p = split1(T[(nc + j) * 68 + d]);     h0[j] = p.h; l0[j] = p.l;
            bfpair q = split1(T[(nc + 8 + j) * 68 + d]); h1[j] = q.h; l1[j] = q.l;
        }
        __bf16* dsth = XThi + (size_t)d * NNODE + n0 + nc;
        __bf16* dstl = XTlo + (size_t)d * NNODE + n0 + nc;
        *(bf16x8*)dsth = h0; *(bf16x8*)(dsth + 8) = h1;
        *(bf16x8*)dstl = l0; *(bf16x8*)(dstl + 8) = l1;
    }

    if (bx < 2) {
        int c  = bx * 256 + tid;          // 0..511
        int o  = c >> 3;                  // 0..63
        int d0 = (c & 7) * 8;             // 0..56
        bf16x8 h, l;
        #pragma unroll
        for (int i = 0; i < 8; ++i) {
            bfpair p = split1(theta[(size_t)(d0 + i) * ND + o]);
            h[i] = p.h; l[i] = p.l;
        }
        *(bf16x8*)(ws + WTHI + (size_t)o * 64 + d0) = h;
        *(bf16x8*)(ws + WTLO + (size_t)o * 64 + d0) = l;
    }
}

// ---------------------------------------------------------------------------
// spattn3: grid 768 (8 XCD-chunks x 12 g x 8 row-blocks), 256 threads,
// 4 waves x 32 rows. Barrier-free main loop; K/V frags direct from ws.
// ---------------------------------------------------------------------------
__global__ void __launch_bounds__(256, 3)
spattn3(const __bf16* __restrict__ ws, const float* __restrict__ adj,
        float* __restrict__ out)
{
    __shared__ __align__(16) char smem[SMEM3];
    float* Pm = (float*)smem;               // [128][PSTRIDE] f32, wave-private

    const int tid  = threadIdx.x;
    const int wave = tid >> 6;              // 0..3, owns rows wave*32..+31
    const int lane = tid & 63;
    const int l16  = lane & 15;
    const int quad = lane >> 4;

    // XCD-aware swizzle: hw XCD = bx&7; give each XCD 12 whole g's with all
    // 8 row-blocks -> per-XCD L2 working set 12*512KB instead of 96*512KB.
    const int bx   = blockIdx.x;
    const int xcd  = bx & 7;
    const int idx  = bx >> 3;               // 0..95
    const int g    = xcd * 12 + (idx % 12); // 0..95
    const int rblk = idx / 12;              // 0..7
    const int bb   = g / NT;
    const int tt   = g - bb * NT;
    const int row0 = rblk * 128;

    const __bf16* xh  = ws + WXHI  + (size_t)g * 65536;
    const __bf16* xl  = ws + WXLO  + (size_t)g * 65536;
    const __bf16* xth = ws + WXTHI + (size_t)g * 65536;
    const __bf16* xtl = ws + WXTLO + (size_t)g * 65536;

    // ---- Q fragments straight from split arrays (unscaled) ----
    bf16x8 qhi[2][2], qlo[2][2];
    #pragma unroll
    for (int mt = 0; mt < 2; ++mt) {
        const __bf16* q0 = xh + (size_t)(row0 + wave*32 + mt*16 + l16) * 64 + quad*8;
        const __bf16* q1 = xl + (size_t)(row0 + wave*32 + mt*16 + l16) * 64 + quad*8;
        #pragma unroll
        for (int ks = 0; ks < 2; ++ks) {
            qhi[mt][ks] = *(const bf16x8*)(q0 + ks*32);
            qlo[mt][ks] = *(const bf16x8*)(q1 + ks*32);
        }
    }

    const floatx4 vzero = {0.f, 0.f, 0.f, 0.f};
    floatx4 acc[2][4];
    #pragma unroll
    for (int mt = 0; mt < 2; ++mt)
        #pragma unroll
        for (int dt = 0; dt < 4; ++dt)
            acc[mt][dt] = vzero;
    float lpart[2][4] = {{0.f,0.f,0.f,0.f},{0.f,0.f,0.f,0.f}};

    for (int ct = 0; ct < 32; ++ct) {
        const int key0 = ct * 32;

        // K B-frags direct from global (b128, 64B-segment coalesced, L2-hot)
        bf16x8 kh[2][2], kl[2][2];          // [ks][nt]
        #pragma unroll
        for (int nt = 0; nt < 2; ++nt) {
            const __bf16* kr0 = xh + (size_t)(key0 + nt*16 + l16) * 64 + quad*8;
            const __bf16* kr1 = xl + (size_t)(key0 + nt*16 + l16) * 64 + quad*8;
            #pragma unroll
            for (int ks = 0; ks < 2; ++ks) {
                kh[ks][nt] = *(const bf16x8*)(kr0 + ks*32);
                kl[ks][nt] = *(const bf16x8*)(kr1 + ks*32);
            }
        }
        // adj loads (L2-hot; used only after the QK burst + exp -> slack)
        float av[2][2][4];
        #pragma unroll
        for (int mt = 0; mt < 2; ++mt)
            #pragma unroll
            for (int nt = 0; nt < 2; ++nt)
                #pragma unroll
                for (int r = 0; r < 4; ++r)
                    av[mt][nt][r] = adj[(size_t)(row0 + wave*32 + mt*16 + quad*4 + r) * NNODE
                                        + key0 + nt*16 + l16];

        // ---- S = Q K^T (3-term split bf16), raw scale ----
        floatx4 S[2][2] = {{vzero, vzero}, {vzero, vzero}};
        #pragma unroll
        for (int ks = 0; ks < 2; ++ks)
            #pragma unroll
            for (int nt = 0; nt < 2; ++nt)
                #pragma unroll
                for (int mt = 0; mt < 2; ++mt) {
                    S[mt][nt] = MFMA(qhi[mt][ks], kh[ks][nt], S[mt][nt]);
                    S[mt][nt] = MFMA(qlo[mt][ks], kh[ks][nt], S[mt][nt]);
                    S[mt][nt] = MFMA(qhi[mt][ks], kl[ks][nt], S[mt][nt]);
                }

        // V B-frags issue now; consumed after the exp/P phase (latency slack)
        bf16x8 vh[4], vl[4];
        #pragma unroll
        for (int dt = 0; dt < 4; ++dt) {
            vh[dt] = *(const bf16x8*)(xth + (size_t)(dt*16 + l16) * NNODE + key0 + quad*8);
            vl[dt] = *(const bf16x8*)(xtl + (size_t)(dt*16 + l16) * NNODE + key0 + quad*8);
        }

        // ---- exp2 (scale folded), denominator, P = adj*exp -> LDS ----
        #pragma unroll
        for (int mt = 0; mt < 2; ++mt)
            #pragma unroll
            for (int nt = 0; nt < 2; ++nt)
                #pragma unroll
                for (int r = 0; r < 4; ++r) {
                    float w = __builtin_amdgcn_exp2f(S[mt][nt][r] * QSCALE);
                    lpart[mt][r] += w;
                    Pm[(wave*32 + mt*16 + quad*4 + r)*PSTRIDE + nt*16 + l16] = av[mt][nt][r] * w;
                }

        // ---- P A-frags back from wave-private LDS (no barrier needed) ----
        bf16x8 pah[2], pal[2];
        #pragma unroll
        for (int mt = 0; mt < 2; ++mt) {
            const float* pp = Pm + (wave*32 + mt*16 + l16)*PSTRIDE + quad*8;
            floatx4 p0 = *(const floatx4*)pp;
            floatx4 p1 = *(const floatx4*)(pp + 4);
            #pragma unroll
            for (int i = 0; i < 4; ++i) {
                bfpair q0 = split1(p0[i]); pah[mt][i]   = q0.h; pal[mt][i]   = q0.l;
                bfpair q1 = split1(p1[i]); pah[mt][4+i] = q1.h; pal[mt][4+i] = q1.l;
            }
        }
        // ---- agg += P . V (3-term split) ----
        #pragma unroll
        for (int dt = 0; dt < 4; ++dt)
            #pragma unroll
            for (int mt = 0; mt < 2; ++mt) {
                acc[mt][dt] = MFMA(pah[mt], vh[dt], acc[mt][dt]);
                acc[mt][dt] = MFMA(pal[mt], vh[dt], acc[mt][dt]);
                acc[mt][dt] = MFMA(pah[mt], vl[dt], acc[mt][dt]);
            }
    }

    // ---- denominator reduce across the 16 lanes of each quad-group ----
    float linv[2][4];
    #pragma unroll
    for (int mt = 0; mt < 2; ++mt)
        #pragma unroll
        for (int r = 0; r < 4; ++r) {
            float lv = lpart[mt][r];
            lv += __shfl_xor(lv, 1);
            lv += __shfl_xor(lv, 2);
            lv += __shfl_xor(lv, 4);
            lv += __shfl_xor(lv, 8);
            linv[mt][r] = 1.0f / lv;
        }

    // ---- epilogue: out = relu((agg/l) @ theta), split-bf16 MFMA ----
    __syncthreads();                       // all waves done with their P rows
    float* AG = (float*)smem;              // [128][AGSTRIDE] overlay
    #pragma unroll
    for (int mt = 0; mt < 2; ++mt)
        #pragma unroll
        for (int dt = 0; dt < 4; ++dt)
            #pragma unroll
            for (int r = 0; r < 4; ++r)
                AG[(wave*32 + mt*16 + quad*4 + r)*AGSTRIDE + dt*16 + l16]
                    = acc[mt][dt][r] * linv[mt][r];

    // theta B-frags from pre-split theta^T (b128, zero conversion)
    const __bf16* Th = ws + WTHI;
    const __bf16* Tl = ws + WTLO;
    bf16x8 th[4][2], tlw[4][2];
    #pragma unroll
    for (int ot = 0; ot < 4; ++ot)
        #pragma unroll
        for (int ks = 0; ks < 2; ++ks) {
            th[ot][ks]  = *(const bf16x8*)(Th + (size_t)(ot*16 + l16)*64 + ks*32 + quad*8);
            tlw[ot][ks] = *(const bf16x8*)(Tl + (size_t)(ot*16 + l16)*64 + ks*32 + quad*8);
        }

    floatx4 oacc[2][4];
    #pragma unroll
    for (int mt = 0; mt < 2; ++mt)
        #pragma unroll
        for (int ot = 0; ot < 4; ++ot)
            oacc[mt][ot] = vzero;
    __syncthreads();                       // AG region fully written
    #pragma unroll
    for (int ks = 0; ks < 2; ++ks) {
        bf16x8 ah[2], al[2];
        #pragma unroll
        for (int mt = 0; mt < 2; ++mt) {
            const float* ap = AG + (wave*32 + mt*16 + l16)*AGSTRIDE + ks*32 + quad*8;
            floatx4 a0 = *(const floatx4*)ap;
            floatx4 a1 = *(const floatx4*)(ap + 4);
            #pragma unroll
            for (int i = 0; i < 4; ++i) {
                bfpair q0 = split1(a0[i]); ah[mt][i]   = q0.h; al[mt][i]   = q0.l;
                bfpair q1 = split1(a1[i]); ah[mt][4+i] = q1.h; al[mt][4+i] = q1.l;
            }
        }
        #pragma unroll
        for (int ot = 0; ot < 4; ++ot)
            #pragma unroll
            for (int mt = 0; mt < 2; ++mt) {
                oacc[mt][ot] = MFMA(ah[mt], th[ot][ks], oacc[mt][ot]);
                oacc[mt][ot] = MFMA(al[mt], th[ot][ks], oacc[mt][ot]);
                oacc[mt][ot] = MFMA(ah[mt], tlw[ot][ks], oacc[mt][ot]);
            }
    }

    float* obase = out + (size_t)bb * (NNODE * XROW) + tt * ND;
    #pragma unroll
    for (int mt = 0; mt < 2; ++mt)
        #pragma unroll
        for (int ot = 0; ot < 4; ++ot)
            #pragma unroll
            for (int r = 0; r < 4; ++r) {
                float v = oacc[mt][ot][r];
                obase[(size_t)(row0 + wave*32 + mt*16 + quad*4 + r) * XROW + ot*16 + l16]
                    = v > 0.f ? v : 0.f;
            }
}

// ---------------------------------------------------------------------------
// Fallback: verified R5 kernel (used only if workspace is too small).
// ---------------------------------------------------------------------------
__global__ void __launch_bounds__(256, 2)
spattn_fb(const float* __restrict__ x, const float* __restrict__ adj,
          const float* __restrict__ theta, float* __restrict__ out)
{
    __shared__ __align__(16) char smem[SMEM_FB];
    __bf16* Khi = (__bf16*)(smem + OFF_KHI);
    __bf16* Klo = (__bf16*)(smem + OFF_KLO);
    __bf16* Vhi = (__bf16*)(smem + OFF_VHI);
    __bf16* Vlo = (__bf16*)(smem + OFF_VLO);
    float*  Pm  = (float*)(smem + OFF_P);

    const int tid  = threadIdx.x;
    const int wave = tid >> 6;
    const int lane = tid & 63;
    const int l16  = lane & 15;
    const int quad = lane >> 4;

    const int bx   = blockIdx.x;
    const int g    = bx >> 3;
    const int rblk = bx & 7;
    const int bb   = g / NT;
    const int tt   = g - bb * NT;
    const int row0 = rblk * 128;

    const float* xbase = x + (size_t)bb * (NNODE * XROW) + tt * ND;

    bf16x8 qhi[2][2], qlo[2][2];
    #pragma unroll
    for (int mt = 0; mt < 2; ++mt) {
        const float* qsrc = xbase + (size_t)(row0 + wave*32 + mt*16 + l16) * XROW;
        #pragma unroll
        for (int ks = 0; ks < 2; ++ks) {
            floatx4 f0 = *(const floatx4*)(qsrc + ks*32 + quad*8);
            floatx4 f1 = *(const floatx4*)(qsrc + ks*32 + quad*8 + 4);
            #pragma unroll
            for (int i = 0; i < 4; ++i) {
                bfpair p0 = split1(f0[i]*QSCALE);
                qhi[mt][ks][i]   = p0.h; qlo[mt][ks][i]   = p0.l;
                bfpair p1 = split1(f1[i]*QSCALE);
                qhi[mt][ks][4+i] = p1.h; qlo[mt][ks][4+i] = p1.l;
            }
        }
    }

    const floatx4 vzero = {0.f, 0.f, 0.f, 0.f};
    floatx4 acc[2][4];
    #pragma unroll
    for (int mt = 0; mt < 2; ++mt)
        #pragma unroll
        for (int dt = 0; dt < 4; ++dt)
            acc[mt][dt] = vzero;
    float lpart[2][4] = {{0.f,0.f,0.f,0.f},{0.f,0.f,0.f,0.f}};

    const int skey = tid >> 3;
    const int sd0  = (tid & 7) * 8;
    const int svd  = tid >> 2;
    const int svk0 = (tid & 3) * 8;
    floatx4 kf0, kf1;
    float vf[8];

    {
        const float* ksrc = xbase + (size_t)skey * XROW + sd0;
        kf0 = *(const floatx4*)ksrc;
        kf1 = *(const floatx4*)(ksrc + 4);
        const float* vsrc = xbase + (size_t)svk0 * XROW + svd;
        #pragma unroll
        for (int i = 0; i < 8; ++i) vf[i] = vsrc[i * XROW];
    }

    for (int ct = 0; ct < 32; ++ct) {
        const int key0 = ct * 32;
        __syncthreads();
        {
            bf16x8 h, l;
            #pragma unroll
            for (int i = 0; i < 4; ++i) {
                bfpair p0 = split1(kf0[i]); h[i]   = p0.h; l[i]   = p0.l;
                bfpair p1 = split1(kf1[i]); h[4+i] = p1.h; l[4+i] = p1.l;
            }
            *(bf16x8*)(Khi + skey*KSTRIDE + sd0) = h;
            *(bf16x8*)(Klo + skey*KSTRIDE + sd0) = l;
            bf16x8 vh, vl;
            #pragma unroll
            for (int i = 0; i < 8; ++i) {
                bfpair p = split1(vf[i]); vh[i] = p.h; vl[i] = p.l;
            }
            *(bf16x8*)(Vhi + svd*VSTRIDE + svk0) = vh;
            *(bf16x8*)(Vlo + svd*VSTRIDE + svk0) = vl;
        }
        __syncthreads();
        if (ct < 31) {
            const int nk = key0 + 32;
            const float* ksrc = xbase + (size_t)(nk + skey) * XROW + sd0;
            kf0 = *(const floatx4*)ksrc;
            kf1 = *(const floatx4*)(ksrc + 4);
            const float* vsrc = xbase + (size_t)(nk + svk0) * XROW + svd;
            #pragma unroll
            for (int i = 0; i < 8; ++i) vf[i] = vsrc[i * XROW];
        }
        float av[2][2][4];
        #pragma unroll
        for (int mt = 0; mt < 2; ++mt)
            #pragma unroll
            for (int nt = 0; nt < 2; ++nt)
                #pragma unroll
                for (int r = 0; r < 4; ++r)
                    av[mt][nt][r] = adj[(size_t)(row0 + wave*32 + mt*16 + quad*4 + r) * NNODE
                                        + key0 + nt*16 + l16];

        floatx4 S[2][2] = {{vzero, vzero}, {vzero, vzero}};
        #pragma unroll
        for (int ks = 0; ks < 2; ++ks) {
            #pragma unroll
            for (int nt = 0; nt < 2; ++nt) {
                bf16x8 bh = *(const bf16x8*)(Khi + (nt*16 + l16)*KSTRIDE + ks*32 + quad*8);
                bf16x8 bl = *(const bf16x8*)(Klo + (nt*16 + l16)*KSTRIDE + ks*32 + quad*8);
                #pragma unroll
                for (int mt = 0; mt < 2; ++mt) {
                    S[mt][nt] = MFMA(qhi[mt][ks], bh, S[mt][nt]);
                    S[mt][nt] = MFMA(qlo[mt][ks], bh, S[mt][nt]);
                    S[mt][nt] = MFMA(qhi[mt][ks], bl, S[mt][nt]);
                }
            }
        }
        #pragma unroll
        for (int mt = 0; mt < 2; ++mt)
            #pragma unroll
            for (int nt = 0; nt < 2; ++nt)
                #pragma unroll
                for (int r = 0; r < 4; ++r) {
                    float w = __builtin_amdgcn_exp2f(S[mt][nt][r]);
                    lpart[mt][r] += w;
                    Pm[(wave*32 + mt*16 + quad*4 + r)*PSTRIDE + nt*16 + l16] = av[mt][nt][r] * w;
                }
        bf16x8 pah[2], pal[2];
        #pragma unroll
        for (int mt = 0; mt < 2; ++mt) {
            const float* pp = Pm + (wave*32 + mt*16 + l16)*PSTRIDE + quad*8;
            floatx4 p0 = *(const floatx4*)pp;
            floatx4 p1 = *(const floatx4*)(pp + 4);
            #pragma unroll
            for (int i = 0; i < 4; ++i) {
                bfpair q0 = split1(p0[i]); pah[mt][i]   = q0.h; pal[mt][i]   = q0.l;
                bfpair q1 = split1(p1[i]); pah[mt][4+i] = q1.h; pal[mt][4+i] = q1.l;
            }
        }
        #pragma unroll
        for (int dt = 0; dt < 4; ++dt) {
            bf16x8 vh = *(const bf16x8*)(Vhi + (dt*16 + l16)*VSTRIDE + quad*8);
            bf16x8 vl = *(const bf16x8*)(Vlo + (dt*16 + l16)*VSTRIDE + quad*8);
            #pragma unroll
            for (int mt = 0; mt < 2; ++mt) {
                acc[mt][dt] = MFMA(pah[mt], vh, acc[mt][dt]);
                acc[mt][dt] = MFMA(pal[mt], vh, acc[mt][dt]);
                acc[mt][dt] = MFMA(pah[mt], vl, acc[mt][dt]);
            }
        }
    }

    float linv[2][4];
    #pragma unroll
    for (int mt = 0; mt < 2; ++mt)
        #pragma unroll
        for (int r = 0; r < 4; ++r) {
            float lv = lpart[mt][r];
            lv += __shfl_xor(lv, 1);
            lv += __shfl_xor(lv, 2);
            lv += __shfl_xor(lv, 4);
            lv += __shfl_xor(lv, 8);
            linv[mt][r] = 1.0f / lv;
        }

    __syncthreads();
    float* AG = (float*)smem;
    #pragma unroll
    for (int mt = 0; mt < 2; ++mt)
        #pragma unroll
        for (int dt = 0; dt < 4; ++dt)
            #pragma unroll
            for (int r = 0; r < 4; ++r)
                AG[(wave*32 + mt*16 + quad*4 + r)*AGSTRIDE + dt*16 + l16]
                    = acc[mt][dt][r] * linv[mt][r];

    bf16x8 th[4][2], tl[4][2];
    #pragma unroll
    for (int ot = 0; ot < 4; ++ot)
        #pragma unroll
        for (int ks = 0; ks < 2; ++ks)
            #pragma unroll
            for (int j = 0; j < 8; ++j) {
                float tv = theta[(ks*32 + quad*8 + j)*ND + ot*16 + l16];
                bfpair p = split1(tv);
                th[ot][ks][j] = p.h; tl[ot][ks][j] = p.l;
            }

    floatx4 oacc[2][4];
    #pragma unroll
    for (int mt = 0; mt < 2; ++mt)
        #pragma unroll
        for (int ot = 0; ot < 4; ++ot)
            oacc[mt][ot] = vzero;
    __syncthreads();
    #pragma unroll
    for (int ks = 0; ks < 2; ++ks) {
        bf16x8 ah[2], al[2];
        #pragma unroll
        for (int mt = 0; mt < 2; ++mt) {
            const float* ap = AG + (wave*32 + mt*16 + l16)*AGSTRIDE + ks*32 + quad*8;
            floatx4 a0 = *(const floatx4*)ap;
            floatx4 a1 = *(const floatx4*)(ap + 4);
            #pragma unroll
            for (int i = 0; i < 4; ++i) {
                bfpair q0 = split1(a0[i]); ah[mt][i]   = q0.h; al[mt][i]   = q0.l;
                bfpair q1 = split1(a1[i]); ah[mt][4+i] = q1.h; al[mt][4+i] = q1.l;
            }
        }
        #pragma unroll
        for (int ot = 0; ot < 4; ++ot)
            #pragma unroll
            for (int mt = 0; mt < 2; ++mt) {
                oacc[mt][ot] = MFMA(ah[mt], th[ot][ks], oacc[mt][ot]);
                oacc[mt][ot] = MFMA(al[mt], th[ot][ks], oacc[mt][ot]);
                oacc[mt][ot] = MFMA(ah[mt], tl[ot][ks], oacc[mt][ot]);
            }
    }

    float* obase = out + (size_t)bb * (NNODE * XROW) + tt * ND;
    #pragma unroll
    for (int mt = 0; mt < 2; ++mt)
        #pragma unroll
        for (int ot = 0; ot < 4; ++ot)
            #pragma unroll
            for (int r = 0; r < 4; ++r) {
                float v = oacc[mt][ot][r];
                obase[(size_t)(row0 + wave*32 + mt*16 + quad*4 + r) * XROW + ot*16 + l16]
                    = v > 0.f ? v : 0.f;
            }
}

extern "C" void kernel_launch(void* const* d_in, const int* in_sizes, int n_in,
                              void* d_out, int out_size, void* d_ws, size_t ws_size,
                              hipStream_t stream) {
    (void)in_sizes; (void)n_in; (void)out_size;
    const float* x     = (const float*)d_in[0];
    const float* adj   = (const float*)d_in[1];
    const float* theta = (const float*)d_in[2];
    float* out = (float*)d_out;
    if (d_ws != nullptr && ws_size >= WS_BYTES) {
        __bf16* ws = (__bf16*)d_ws;
        presplit<<<dim3(1536), dim3(256), 0, stream>>>(x, theta, ws);
        spattn3<<<dim3(768), dim3(256), 0, stream>>>(ws, adj, out);
    } else {
        spattn_fb<<<dim3(768), dim3(256), 0, stream>>>(x, adj, theta, out);
    }
}

// Round 4
// 172.594 us; speedup vs baseline: 1.5972x; 1.5972x over previous
//
#include <hip/hip_runtime.h>

// PositionWiseSpatialAttention — fused flash-style kernel, MI355X gfx950.
//
// R9 = merge of the three harness-verified best pieces:
//  - presplit ws (R7/R8, verified): x -> {hi,lo} bf16 row-major + transposed,
//    theta^T split. Staging math done once, off the hot loop.
//  - spattn4: R5's PROVEN tiling + sync structure (128-row blocks, 4 waves x
//    32 rows, single-buffer K/V LDS, 2 barriers/iter, reg-prefetch of next
//    tile) but staging is now 4 pure b128 copies from ws (R7-verified) —
//    no split VALU between the barriers. V staging reads the transposed ws
//    (contiguous b128) instead of 8 strided dwords. Q and theta frags b128
//    direct from ws (R8-verified indexing). Block order bx = rblk*96 + g
//    puts all 8 row-blocks of a g on one XCD (96 % 8 == 0) -> K/V L2-local.
// R8 post-mortem: removing K/V LDS staging made the loop L2-latency-bound
// (all counters idle); staging amortizes fragment reads 4-waves-wide and
// the barriers group the latency. R7 post-mortem: 64-row tiles doubled
// total LDS-read traffic; 128-row tiles halve it back.
// Math identical to R5/R7 (same split values, scale folded into exp2).

#define NB    8
#define NT    12
#define NNODE 1024
#define ND    64
#define XROW  768   /* NT*ND: stride between consecutive n for fixed (b,t) */
#define NG    96    /* NB*NT */

typedef __bf16 bf16x8 __attribute__((ext_vector_type(8)));
typedef __bf16 bf16x4 __attribute__((ext_vector_type(4)));
typedef float  floatx4 __attribute__((ext_vector_type(4)));

#define MFMA(a,b,c) __builtin_amdgcn_mfma_f32_16x16x32_bf16((a),(b),(c),0,0,0)

#define QSCALE 0.18033688011112042f   /* 0.125 * log2(e) */

// LDS layout (bytes); all row strides keep 16B alignment for b128 ops.
#define KSTRIDE 72   /* bf16 per K row: 144 B */
#define VSTRIDE 40   /* bf16 per V row:  80 B */
#define PSTRIDE 36   /* f32  per P row: 144 B */
#define AGSTRIDE 68  /* f32  per AG row (epilogue overlay) */
#define OFF_KHI 0
#define OFF_KLO 4608
#define OFF_VHI 9216
#define OFF_VLO 14336
#define OFF_P   19456
#define SMEM_BYTES (19456 + 128*PSTRIDE*4)   /* 37888 */

// workspace element offsets (__bf16 units)
#define WXHI  0          /* [96][1024][64] row-major hi  */
#define WXLO  6291456
#define WXTHI 12582912   /* [96][64][1024] transposed hi */
#define WXTLO 18874368
#define WTHI  25165824   /* [64 o][64 d] theta^T hi      */
#define WTLO  25169920
#define WS_BYTES 50348032ULL

struct bfpair { __bf16 h, l; };

// error-compensated split: hi = RNE(f) via native fptrunc, lo = RNE(f - hi).
// |f - hi - lo| ~ 2^-17 |f|.
__device__ __forceinline__ bfpair split1(float f) {
    bfpair r;
    __bf16 hb = (__bf16)f;
    float hf = __builtin_bit_cast(float,
                   (unsigned)__builtin_bit_cast(unsigned short, hb) << 16);
    r.h = hb;
    r.l = (__bf16)(f - hf);
    return r;
}

// ---------------------------------------------------------------------------
// presplit: grid 1536 (96 g x 16 n-blocks), 256 threads. (R7/R8, verified)
// ---------------------------------------------------------------------------
__global__ void __launch_bounds__(256)
presplit(const float* __restrict__ x, const float* __restrict__ theta,
         __bf16* __restrict__ ws)
{
    __shared__ __align__(16) float T[64 * 68];
    const int tid  = threadIdx.x;
    const int bx   = blockIdx.x;
    const int g    = bx >> 4;
    const int nblk = bx & 15;
    const int bb   = g / NT;
    const int tt   = g - bb * NT;
    const int n0   = nblk * 64;

    __bf16* Xhi  = ws + WXHI  + (size_t)g * 65536;
    __bf16* Xlo  = ws + WXLO  + (size_t)g * 65536;
    __bf16* XThi = ws + WXTHI + (size_t)g * 65536;
    __bf16* XTlo = ws + WXTLO + (size_t)g * 65536;
    const float* xg = x + (size_t)bb * (NNODE * XROW) + (size_t)tt * ND;

    #pragma unroll
    for (int i = 0; i < 4; ++i) {
        int chunk = i * 256 + tid;        // 0..1023
        int n  = chunk >> 4;              // 0..63
        int c4 = (chunk & 15) * 4;        // 0..60
        floatx4 f = *(const floatx4*)(xg + (size_t)(n0 + n) * XROW + c4);
        *(floatx4*)(T + n * 68 + c4) = f;
        bf16x4 h, l;
        #pragma unroll
        for (int j = 0; j < 4; ++j) {
            bfpair p = split1(f[j]); h[j] = p.h; l[j] = p.l;
        }
        *(bf16x4*)(Xhi + (size_t)(n0 + n) * 64 + c4) = h;
        *(bf16x4*)(Xlo + (size_t)(n0 + n) * 64 + c4) = l;
    }
    __syncthreads();

    {
        const int d  = tid >> 2;          // 0..63
        const int nc = (tid & 3) * 16;    // 0..48
        bf16x8 h0, l0, h1, l1;
        #pragma unroll
        for (int j = 0; j < 8; ++j) {
            bfpair p = split1(T[(nc + j) * 68 + d]);     h0[j] = p.h; l0[j] = p.l;
            bfpair q = split1(T[(nc + 8 + j) * 68 + d]); h1[j] = q.h; l1[j] = q.l;
        }
        __bf16* dsth = XThi + (size_t)d * NNODE + n0 + nc;
        __bf16* dstl = XTlo + (size_t)d * NNODE + n0 + nc;
        *(bf16x8*)dsth = h0; *(bf16x8*)(dsth + 8) = h1;
        *(bf16x8*)dstl = l0; *(bf16x8*)(dstl + 8) = l1;
    }

    if (bx < 2) {
        int c  = bx * 256 + tid;          // 0..511
        int o  = c >> 3;                  // 0..63
        int d0 = (c & 7) * 8;             // 0..56
        bf16x8 h, l;
        #pragma unroll
        for (int i = 0; i < 8; ++i) {
            bfpair p = split1(theta[(size_t)(d0 + i) * ND + o]);
            h[i] = p.h; l[i] = p.l;
        }
        *(bf16x8*)(ws + WTHI + (size_t)o * 64 + d0) = h;
        *(bf16x8*)(ws + WTLO + (size_t)o * 64 + d0) = l;
    }
}

// ---------------------------------------------------------------------------
// spattn4: grid 768 (bx = rblk*96 + g), 256 threads, 4 waves x 32 rows.
// R5 sync structure; copy-only staging from presplit ws.
// ---------------------------------------------------------------------------
__global__ void __launch_bounds__(256, 3)
spattn4(const __bf16* __restrict__ ws, const float* __restrict__ adj,
        float* __restrict__ out)
{
    __shared__ __align__(16) char smem[SMEM_BYTES];
    __bf16* Khi = (__bf16*)(smem + OFF_KHI);
    __bf16* Klo = (__bf16*)(smem + OFF_KLO);
    __bf16* Vhi = (__bf16*)(smem + OFF_VHI);
    __bf16* Vlo = (__bf16*)(smem + OFF_VLO);
    float*  Pm  = (float*)(smem + OFF_P);

    const int tid  = threadIdx.x;
    const int wave = tid >> 6;          // 0..3, owns rows wave*32..+31
    const int lane = tid & 63;
    const int l16  = lane & 15;
    const int quad = lane >> 4;

    // bx = rblk*96 + g: all 8 row-blocks of a g share bx%8 -> same XCD.
    const int bx   = blockIdx.x;
    const int g    = bx % NG;           // 0..95
    const int rblk = bx / NG;           // 0..7
    const int bb   = g / NT;
    const int tt   = g - bb * NT;
    const int row0 = rblk * 128;

    const __bf16* xh  = ws + WXHI  + (size_t)g * 65536;
    const __bf16* xl  = ws + WXLO  + (size_t)g * 65536;
    const __bf16* xth = ws + WXTHI + (size_t)g * 65536;
    const __bf16* xtl = ws + WXTLO + (size_t)g * 65536;

    // ---- Q fragments b128 direct from split arrays (R8-verified map) ----
    bf16x8 qhi[2][2], qlo[2][2];
    #pragma unroll
    for (int mt = 0; mt < 2; ++mt) {
        const __bf16* q0 = xh + (size_t)(row0 + wave*32 + mt*16 + l16) * 64 + quad*8;
        const __bf16* q1 = xl + (size_t)(row0 + wave*32 + mt*16 + l16) * 64 + quad*8;
        #pragma unroll
        for (int ks = 0; ks < 2; ++ks) {
            qhi[mt][ks] = *(const bf16x8*)(q0 + ks*32);
            qlo[mt][ks] = *(const bf16x8*)(q1 + ks*32);
        }
    }

    const floatx4 vzero = {0.f, 0.f, 0.f, 0.f};
    floatx4 acc[2][4];
    #pragma unroll
    for (int mt = 0; mt < 2; ++mt)
        #pragma unroll
        for (int dt = 0; dt < 4; ++dt)
            acc[mt][dt] = vzero;
    float lpart[2][4] = {{0.f,0.f,0.f,0.f},{0.f,0.f,0.f,0.f}};

    // staging maps (R5 geometry; V now from transposed ws, contiguous b128)
    const int skey = tid >> 3;          // 0..31
    const int sd0  = (tid & 7) * 8;     // 0..56
    const int svd  = tid >> 2;          // 0..63
    const int svk0 = (tid & 3) * 8;     // 0..24

    bf16x8 kh, kl, vhs, vls;            // register prefetch (tile 0)
    kh  = *(const bf16x8*)(xh  + (size_t)skey * 64 + sd0);
    kl  = *(const bf16x8*)(xl  + (size_t)skey * 64 + sd0);
    vhs = *(const bf16x8*)(xth + (size_t)svd * NNODE + svk0);
    vls = *(const bf16x8*)(xtl + (size_t)svd * NNODE + svk0);

    for (int ct = 0; ct < 32; ++ct) {
        const int key0 = ct * 32;
        __syncthreads();                       // prior tile's LDS reads done
        *(bf16x8*)(Khi + skey*KSTRIDE + sd0) = kh;
        *(bf16x8*)(Klo + skey*KSTRIDE + sd0) = kl;
        *(bf16x8*)(Vhi + svd*VSTRIDE + svk0) = vhs;
        *(bf16x8*)(Vlo + svd*VSTRIDE + svk0) = vls;
        __syncthreads();                       // staging visible
        if (ct < 31) { // register prefetch of next tile, overlaps compute
            const int nk = key0 + 32;
            kh  = *(const bf16x8*)(xh  + (size_t)(nk + skey) * 64 + sd0);
            kl  = *(const bf16x8*)(xl  + (size_t)(nk + skey) * 64 + sd0);
            vhs = *(const bf16x8*)(xth + (size_t)svd * NNODE + nk + svk0);
            vls = *(const bf16x8*)(xtl + (size_t)svd * NNODE + nk + svk0);
        }
        // adj prefetch (L2-hot; consumed after the QK burst -> latency slack)
        float av[2][2][4];
        #pragma unroll
        for (int mt = 0; mt < 2; ++mt)
            #pragma unroll
            for (int nt = 0; nt < 2; ++nt)
                #pragma unroll
                for (int r = 0; r < 4; ++r)
                    av[mt][nt][r] = adj[(size_t)(row0 + wave*32 + mt*16 + quad*4 + r) * NNODE
                                        + key0 + nt*16 + l16];

        // ---- S = Q K^T (3-term split bf16), raw scale ----
        floatx4 S[2][2] = {{vzero, vzero}, {vzero, vzero}};
        #pragma unroll
        for (int ks = 0; ks < 2; ++ks) {
            #pragma unroll
            for (int nt = 0; nt < 2; ++nt) {
                bf16x8 bh = *(const bf16x8*)(Khi + (nt*16 + l16)*KSTRIDE + ks*32 + quad*8);
                bf16x8 bl = *(const bf16x8*)(Klo + (nt*16 + l16)*KSTRIDE + ks*32 + quad*8);
                #pragma unroll
                for (int mt = 0; mt < 2; ++mt) {
                    S[mt][nt] = MFMA(qhi[mt][ks], bh, S[mt][nt]);
                    S[mt][nt] = MFMA(qlo[mt][ks], bh, S[mt][nt]);
                    S[mt][nt] = MFMA(qhi[mt][ks], bl, S[mt][nt]);
                }
            }
        }
        // ---- exp2 (scale folded), denominator, P = adj*exp -> LDS ----
        #pragma unroll
        for (int mt = 0; mt < 2; ++mt)
            #pragma unroll
            for (int nt = 0; nt < 2; ++nt)
                #pragma unroll
                for (int r = 0; r < 4; ++r) {
                    float w = __builtin_amdgcn_exp2f(S[mt][nt][r] * QSCALE);
                    lpart[mt][r] += w;
                    Pm[(wave*32 + mt*16 + quad*4 + r)*PSTRIDE + nt*16 + l16] = av[mt][nt][r] * w;
                }
        // ---- P A-frags back from wave-private LDS rows ----
        bf16x8 pah[2], pal[2];
        #pragma unroll
        for (int mt = 0; mt < 2; ++mt) {
            const float* pp = Pm + (wave*32 + mt*16 + l16)*PSTRIDE + quad*8;
            floatx4 p0 = *(const floatx4*)pp;
            floatx4 p1 = *(const floatx4*)(pp + 4);
            #pragma unroll
            for (int i = 0; i < 4; ++i) {
                bfpair q0 = split1(p0[i]); pah[mt][i]   = q0.h; pal[mt][i]   = q0.l;
                bfpair q1 = split1(p1[i]); pah[mt][4+i] = q1.h; pal[mt][4+i] = q1.l;
            }
        }
        // ---- agg += P . V (3-term split) ----
        #pragma unroll
        for (int dt = 0; dt < 4; ++dt) {
            bf16x8 vvh = *(const bf16x8*)(Vhi + (dt*16 + l16)*VSTRIDE + quad*8);
            bf16x8 vvl = *(const bf16x8*)(Vlo + (dt*16 + l16)*VSTRIDE + quad*8);
            #pragma unroll
            for (int mt = 0; mt < 2; ++mt) {
                acc[mt][dt] = MFMA(pah[mt], vvh, acc[mt][dt]);
                acc[mt][dt] = MFMA(pal[mt], vvh, acc[mt][dt]);
                acc[mt][dt] = MFMA(pah[mt], vvl, acc[mt][dt]);
            }
        }
    }

    // ---- denominator reduce across the 16 lanes of each quad-group ----
    float linv[2][4];
    #pragma unroll
    for (int mt = 0; mt < 2; ++mt)
        #pragma unroll
        for (int r = 0; r < 4; ++r) {
            float lv = lpart[mt][r];
            lv += __shfl_xor(lv, 1);
            lv += __shfl_xor(lv, 2);
            lv += __shfl_xor(lv, 4);
            lv += __shfl_xor(lv, 8);
            linv[mt][r] = 1.0f / lv;
        }

    // ---- epilogue: out = relu((agg/l) @ theta), split-bf16 MFMA ----
    __syncthreads();                       // everyone done with K/V/P
    float* AG = (float*)smem;              // [128][AGSTRIDE] overlay
    #pragma unroll
    for (int mt = 0; mt < 2; ++mt)
        #pragma unroll
        for (int dt = 0; dt < 4; ++dt)
            #pragma unroll
            for (int r = 0; r < 4; ++r)
                AG[(wave*32 + mt*16 + quad*4 + r)*AGSTRIDE + dt*16 + l16]
                    = acc[mt][dt][r] * linv[mt][r];

    // theta B-frags from pre-split theta^T (b128, zero conversion)
    const __bf16* Th = ws + WTHI;
    const __bf16* Tl = ws + WTLO;
    bf16x8 th[4][2], tlw[4][2];
    #pragma unroll
    for (int ot = 0; ot < 4; ++ot)
        #pragma unroll
        for (int ks = 0; ks < 2; ++ks) {
            th[ot][ks]  = *(const bf16x8*)(Th + (size_t)(ot*16 + l16)*64 + ks*32 + quad*8);
            tlw[ot][ks] = *(const bf16x8*)(Tl + (size_t)(ot*16 + l16)*64 + ks*32 + quad*8);
        }

    floatx4 oacc[2][4];
    #pragma unroll
    for (int mt = 0; mt < 2; ++mt)
        #pragma unroll
        for (int ot = 0; ot < 4; ++ot)
            oacc[mt][ot] = vzero;
    __syncthreads();                       // AG region fully written
    #pragma unroll
    for (int ks = 0; ks < 2; ++ks) {
        bf16x8 ah[2], al[2];
        #pragma unroll
        for (int mt = 0; mt < 2; ++mt) {
            const float* ap = AG + (wave*32 + mt*16 + l16)*AGSTRIDE + ks*32 + quad*8;
            floatx4 a0 = *(const floatx4*)ap;
            floatx4 a1 = *(const floatx4*)(ap + 4);
            #pragma unroll
            for (int i = 0; i < 4; ++i) {
                bfpair q0 = split1(a0[i]); ah[mt][i]   = q0.h; al[mt][i]   = q0.l;
                bfpair q1 = split1(a1[i]); ah[mt][4+i] = q1.h; al[mt][4+i] = q1.l;
            }
        }
        #pragma unroll
        for (int ot = 0; ot < 4; ++ot)
            #pragma unroll
            for (int mt = 0; mt < 2; ++mt) {
                oacc[mt][ot] = MFMA(ah[mt], th[ot][ks], oacc[mt][ot]);
                oacc[mt][ot] = MFMA(al[mt], th[ot][ks], oacc[mt][ot]);
                oacc[mt][ot] = MFMA(ah[mt], tlw[ot][ks], oacc[mt][ot]);
            }
    }

    float* obase = out + (size_t)bb * (NNODE * XROW) + tt * ND;
    #pragma unroll
    for (int mt = 0; mt < 2; ++mt)
        #pragma unroll
        for (int ot = 0; ot < 4; ++ot)
            #pragma unroll
            for (int r = 0; r < 4; ++r) {
                float v = oacc[mt][ot][r];
                obase[(size_t)(row0 + wave*32 + mt*16 + quad*4 + r) * XROW + ot*16 + l16]
                    = v > 0.f ? v : 0.f;
            }
}

// ---------------------------------------------------------------------------
// Fallback: verified R5 kernel (used only if workspace is too small).
// ---------------------------------------------------------------------------
__global__ void __launch_bounds__(256, 2)
spattn_fb(const float* __restrict__ x, const float* __restrict__ adj,
          const float* __restrict__ theta, float* __restrict__ out)
{
    __shared__ __align__(16) char smem[SMEM_BYTES];
    __bf16* Khi = (__bf16*)(smem + OFF_KHI);
    __bf16* Klo = (__bf16*)(smem + OFF_KLO);
    __bf16* Vhi = (__bf16*)(smem + OFF_VHI);
    __bf16* Vlo = (__bf16*)(smem + OFF_VLO);
    float*  Pm  = (float*)(smem + OFF_P);

    const int tid  = threadIdx.x;
    const int wave = tid >> 6;
    const int lane = tid & 63;
    const int l16  = lane & 15;
    const int quad = lane >> 4;

    const int bx   = blockIdx.x;
    const int g    = bx >> 3;
    const int rblk = bx & 7;
    const int bb   = g / NT;
    const int tt   = g - bb * NT;
    const int row0 = rblk * 128;

    const float* xbase = x + (size_t)bb * (NNODE * XROW) + tt * ND;

    bf16x8 qhi[2][2], qlo[2][2];
    #pragma unroll
    for (int mt = 0; mt < 2; ++mt) {
        const float* qsrc = xbase + (size_t)(row0 + wave*32 + mt*16 + l16) * XROW;
        #pragma unroll
        for (int ks = 0; ks < 2; ++ks) {
            floatx4 f0 = *(const floatx4*)(qsrc + ks*32 + quad*8);
            floatx4 f1 = *(const floatx4*)(qsrc + ks*32 + quad*8 + 4);
            #pragma unroll
            for (int i = 0; i < 4; ++i) {
                bfpair p0 = split1(f0[i]*QSCALE);
                qhi[mt][ks][i]   = p0.h; qlo[mt][ks][i]   = p0.l;
                bfpair p1 = split1(f1[i]*QSCALE);
                qhi[mt][ks][4+i] = p1.h; qlo[mt][ks][4+i] = p1.l;
            }
        }
    }

    const floatx4 vzero = {0.f, 0.f, 0.f, 0.f};
    floatx4 acc[2][4];
    #pragma unroll
    for (int mt = 0; mt < 2; ++mt)
        #pragma unroll
        for (int dt = 0; dt < 4; ++dt)
            acc[mt][dt] = vzero;
    float lpart[2][4] = {{0.f,0.f,0.f,0.f},{0.f,0.f,0.f,0.f}};

    const int skey = tid >> 3;
    const int sd0  = (tid & 7) * 8;
    const int svd  = tid >> 2;
    const int svk0 = (tid & 3) * 8;
    floatx4 kf0, kf1;
    float vf[8];

    {
        const float* ksrc = xbase + (size_t)skey * XROW + sd0;
        kf0 = *(const floatx4*)ksrc;
        kf1 = *(const floatx4*)(ksrc + 4);
        const float* vsrc = xbase + (size_t)svk0 * XROW + svd;
        #pragma unroll
        for (int i = 0; i < 8; ++i) vf[i] = vsrc[i * XROW];
    }

    for (int ct = 0; ct < 32; ++ct) {
        const int key0 = ct * 32;
        __syncthreads();
        {
            bf16x8 h, l;
            #pragma unroll
            for (int i = 0; i < 4; ++i) {
                bfpair p0 = split1(kf0[i]); h[i]   = p0.h; l[i]   = p0.l;
                bfpair p1 = split1(kf1[i]); h[4+i] = p1.h; l[4+i] = p1.l;
            }
            *(bf16x8*)(Khi + skey*KSTRIDE + sd0) = h;
            *(bf16x8*)(Klo + skey*KSTRIDE + sd0) = l;
            bf16x8 vh, vl;
            #pragma unroll
            for (int i = 0; i < 8; ++i) {
                bfpair p = split1(vf[i]); vh[i] = p.h; vl[i] = p.l;
            }
            *(bf16x8*)(Vhi + svd*VSTRIDE + svk0) = vh;
            *(bf16x8*)(Vlo + svd*VSTRIDE + svk0) = vl;
        }
        __syncthreads();
        if (ct < 31) {
            const int nk = key0 + 32;
            const float* ksrc = xbase + (size_t)(nk + skey) * XROW + sd0;
            kf0 = *(const floatx4*)ksrc;
            kf1 = *(const floatx4*)(ksrc + 4);
            const float* vsrc = xbase + (size_t)(nk + svk0) * XROW + svd;
            #pragma unroll
            for (int i = 0; i < 8; ++i) vf[i] = vsrc[i * XROW];
        }
        float av[2][2][4];
        #pragma unroll
        for (int mt = 0; mt < 2; ++mt)
            #pragma unroll
            for (int nt = 0; nt < 2; ++nt)
                #pragma unroll
                for (int r = 0; r < 4; ++r)
                    av[mt][nt][r] = adj[(size_t)(row0 + wave*32 + mt*16 + quad*4 + r) * NNODE
                                        + key0 + nt*16 + l16];

        floatx4 S[2][2] = {{vzero, vzero}, {vzero, vzero}};
        #pragma unroll
        for (int ks = 0; ks < 2; ++ks) {
            #pragma unroll
            for (int nt = 0; nt < 2; ++nt) {
                bf16x8 bh = *(const bf16x8*)(Khi + (nt*16 + l16)*KSTRIDE + ks*32 + quad*8);
                bf16x8 bl = *(const bf16x8*)(Klo + (nt*16 + l16)*KSTRIDE + ks*32 + quad*8);
                #pragma unroll
                for (int mt = 0; mt < 2; ++mt) {
                    S[mt][nt] = MFMA(qhi[mt][ks], bh, S[mt][nt]);
                    S[mt][nt] = MFMA(qlo[mt][ks], bh, S[mt][nt]);
                    S[mt][nt] = MFMA(qhi[mt][ks], bl, S[mt][nt]);
                }
            }
        }
        #pragma unroll
        for (int mt = 0; mt < 2; ++mt)
            #pragma unroll
            for (int nt = 0; nt < 2; ++nt)
                #pragma unroll
                for (int r = 0; r < 4; ++r) {
                    float w = __builtin_amdgcn_exp2f(S[mt][nt][r]);
                    lpart[mt][r] += w;
                    Pm[(wave*32 + mt*16 + quad*4 + r)*PSTRIDE + nt*16 + l16] = av[mt][nt][r] * w;
                }
        bf16x8 pah[2], pal[2];
        #pragma unroll
        for (int mt = 0; mt < 2; ++mt) {
            const float* pp = Pm + (wave*32 + mt*16 + l16)*PSTRIDE + quad*8;
            floatx4 p0 = *(const floatx4*)pp;
            floatx4 p1 = *(const floatx4*)(pp + 4);
            #pragma unroll
            for (int i = 0; i < 4; ++i) {
                bfpair q0 = split1(p0[i]); pah[mt][i]   = q0.h; pal[mt][i]   = q0.l;
                bfpair q1 = split1(p1[i]); pah[mt][4+i] = q1.h; pal[mt][4+i] = q1.l;
            }
        }
        #pragma unroll
        for (int dt = 0; dt < 4; ++dt) {
            bf16x8 vh = *(const bf16x8*)(Vhi + (dt*16 + l16)*VSTRIDE + quad*8);
            bf16x8 vl = *(const bf16x8*)(Vlo + (dt*16 + l16)*VSTRIDE + quad*8);
            #pragma unroll
            for (int mt = 0; mt < 2; ++mt) {
                acc[mt][dt] = MFMA(pah[mt], vh, acc[mt][dt]);
                acc[mt][dt] = MFMA(pal[mt], vh, acc[mt][dt]);
                acc[mt][dt] = MFMA(pah[mt], vl, acc[mt][dt]);
            }
        }
    }

    float linv[2][4];
    #pragma unroll
    for (int mt = 0; mt < 2; ++mt)
        #pragma unroll
        for (int r = 0; r < 4; ++r) {
            float lv = lpart[mt][r];
            lv += __shfl_xor(lv, 1);
            lv += __shfl_xor(lv, 2);
            lv += __shfl_xor(lv, 4);
            lv += __shfl_xor(lv, 8);
            linv[mt][r] = 1.0f / lv;
        }

    __syncthreads();
    float* AG = (float*)smem;
    #pragma unroll
    for (int mt = 0; mt < 2; ++mt)
        #pragma unroll
        for (int dt = 0; dt < 4; ++dt)
            #pragma unroll
            for (int r = 0; r < 4; ++r)
                AG[(wave*32 + mt*16 + quad*4 + r)*AGSTRIDE + dt*16 + l16]
                    = acc[mt][dt][r] * linv[mt][r];

    bf16x8 th[4][2], tl[4][2];
    #pragma unroll
    for (int ot = 0; ot < 4; ++ot)
        #pragma unroll
        for (int ks = 0; ks < 2; ++ks)
            #pragma unroll
            for (int j = 0; j < 8; ++j) {
                float tv = theta[(ks*32 + quad*8 + j)*ND + ot*16 + l16];
                bfpair p = split1(tv);
                th[ot][ks][j] = p.h; tl[ot][ks][j] = p.l;
            }

    floatx4 oacc[2][4];
    #pragma unroll
    for (int mt = 0; mt < 2; ++mt)
        #pragma unroll
        for (int ot = 0; ot < 4; ++ot)
            oacc[mt][ot] = vzero;
    __syncthreads();
    #pragma unroll
    for (int ks = 0; ks < 2; ++ks) {
        bf16x8 ah[2], al[2];
        #pragma unroll
        for (int mt = 0; mt < 2; ++mt) {
            const float* ap = AG + (wave*32 + mt*16 + l16)*AGSTRIDE + ks*32 + quad*8;
            floatx4 a0 = *(const floatx4*)ap;
            floatx4 a1 = *(const floatx4*)(ap + 4);
            #pragma unroll
            for (int i = 0; i < 4; ++i) {
                bfpair q0 = split1(a0[i]); ah[mt][i]   = q0.h; al[mt][i]   = q0.l;
                bfpair q1 = split1(a1[i]); ah[mt][4+i] = q1.h; al[mt][4+i] = q1.l;
            }
        }
        #pragma unroll
        for (int ot = 0; ot < 4; ++ot)
            #pragma unroll
            for (int mt = 0; mt < 2; ++mt) {
                oacc[mt][ot] = MFMA(ah[mt], th[ot][ks], oacc[mt][ot]);
                oacc[mt][ot] = MFMA(al[mt], th[ot][ks], oacc[mt][ot]);
                oacc[mt][ot] = MFMA(ah[mt], tl[ot][ks], oacc[mt][ot]);
            }
    }

    float* obase = out + (size_t)bb * (NNODE * XROW) + tt * ND;
    #pragma unroll
    for (int mt = 0; mt < 2; ++mt)
        #pragma unroll
        for (int ot = 0; ot < 4; ++ot)
            #pragma unroll
            for (int r = 0; r < 4; ++r) {
                float v = oacc[mt][ot][r];
                obase[(size_t)(row0 + wave*32 + mt*16 + quad*4 + r) * XROW + ot*16 + l16]
                    = v > 0.f ? v : 0.f;
            }
}

extern "C" void kernel_launch(void* const* d_in, const int* in_sizes, int n_in,
                              void* d_out, int out_size, void* d_ws, size_t ws_size,
                              hipStream_t stream) {
    (void)in_sizes; (void)n_in; (void)out_size;
    const float* x     = (const float*)d_in[0];
    const float* adj   = (const float*)d_in[1];
    const float* theta = (const float*)d_in[2];
    float* out = (float*)d_out;
    if (d_ws != nullptr && ws_size >= WS_BYTES) {
        __bf16* ws = (__bf16*)d_ws;
        presplit<<<dim3(1536), dim3(256), 0, stream>>>(x, theta, ws);
        spattn4<<<dim3(768), dim3(256), 0, stream>>>(ws, adj, out);
    } else {
        spattn_fb<<<dim3(768), dim3(256), 0, stream>>>(x, adj, theta, out);
    }
}

// Round 5
// 171.547 us; speedup vs baseline: 1.6070x; 1.0061x over previous
//
#include <hip/hip_runtime.h>

// PositionWiseSpatialAttention — fused flash-style kernel, MI355X gfx950.
//
// R10: swapped-QK^T, register-resident P.
//  - presplit: as R9 but the transposed V arrays are written with a
//    per-32-key-tile position permutation  c=quad*8+j <-> k=(j>>2)*16+quad*4+(j&3)
//    so the PV B-frag matches P's natural in-register layout.
//  - spattn5: S^T = MFMA(K, Q) (operands swapped; loads IDENTICAL to R9's —
//    A/B frags share the same lane->element map, proven by R5/R9 passing).
//    Output lands col=q=l16, row=key=quad*4+r -> each lane owns P of its own
//    q-row -> P is split to bf16 IN REGISTERS and fed straight to the PV
//    MFMA. The P LDS round-trip (16 ds_write_b32 + 4 conflicting
//    ds_read_b128 per wave-tile; 9.5M conflict cycles = ~15% of R9's time)
//    is deleted. adj is loaded as floatx4 (4 loads vs 16 scalars).
//    Denominator: lane-local partial + shfl_xor(16,32) + 1 bpermute.
//    LDS 34.8KB -> 4 blocks/CU, launch_bounds(256,4) (128 VGPR budget,
//    R9 used 76 — no R6-style spill risk).
// PV contraction order is permuted (bijection) — f32 accumulate reorder only.

#define NB    8
#define NT    12
#define NNODE 1024
#define ND    64
#define XROW  768   /* NT*ND: stride between consecutive n for fixed (b,t) */
#define NG    96    /* NB*NT */

typedef __bf16 bf16x8 __attribute__((ext_vector_type(8)));
typedef __bf16 bf16x4 __attribute__((ext_vector_type(4)));
typedef float  floatx4 __attribute__((ext_vector_type(4)));

#define MFMA(a,b,c) __builtin_amdgcn_mfma_f32_16x16x32_bf16((a),(b),(c),0,0,0)

#define QSCALE 0.18033688011112042f   /* 0.125 * log2(e) */

// LDS layout (bytes); K/V staging only, P lives in registers now.
#define KSTRIDE 72   /* bf16 per K row: 144 B */
#define VSTRIDE 40   /* bf16 per V row:  80 B */
#define AGSTRIDE 68  /* f32 per AG row (epilogue overlay) */
#define OFF_KHI 0
#define OFF_KLO 4608
#define OFF_VHI 9216
#define OFF_VLO 14336
#define SMEM5   (128 * AGSTRIDE * 4)      /* 34816 (>= 19456 staging) */
#define PSTRIDE 36
#define SMEM_FB (19456 + 128*PSTRIDE*4)   /* fallback (R5): 37888 */
#define OFF_P   19456

// workspace element offsets (__bf16 units)
#define WXHI  0          /* [96][1024][64] row-major hi          */
#define WXLO  6291456
#define WVPHI 12582912   /* [96][64][1024] transposed+PERMUTED hi */
#define WVPLO 18874368
#define WTHI  25165824   /* [64 o][64 d] theta^T hi               */
#define WTLO  25169920
#define WS_BYTES 50348032ULL

struct bfpair { __bf16 h, l; };

// error-compensated split: hi = RNE(f) via native fptrunc, lo = RNE(f - hi).
__device__ __forceinline__ bfpair split1(float f) {
    bfpair r;
    __bf16 hb = (__bf16)f;
    float hf = __builtin_bit_cast(float,
                   (unsigned)__builtin_bit_cast(unsigned short, hb) << 16);
    r.h = hb;
    r.l = (__bf16)(f - hf);
    return r;
}

// ---------------------------------------------------------------------------
// presplit: grid 1536 (96 g x 16 n-blocks), 256 threads.
// Row-major split unchanged (R7/R9-verified). Transposed split now writes
// k-PERMUTED positions: position c in each 32-key tile holds key
// k(c) = ((c&7)>>2)*16 + (c>>3)*4 + (c&3).
// ---------------------------------------------------------------------------
__global__ void __launch_bounds__(256)
presplit(const float* __restrict__ x, const float* __restrict__ theta,
         __bf16* __restrict__ ws)
{
    __shared__ __align__(16) float T[64 * 68];
    const int tid  = threadIdx.x;
    const int bx   = blockIdx.x;
    const int g    = bx >> 4;
    const int nblk = bx & 15;
    const int bb   = g / NT;
    const int tt   = g - bb * NT;
    const int n0   = nblk * 64;

    __bf16* Xhi  = ws + WXHI  + (size_t)g * 65536;
    __bf16* Xlo  = ws + WXLO  + (size_t)g * 65536;
    __bf16* VPhi = ws + WVPHI + (size_t)g * 65536;
    __bf16* VPlo = ws + WVPLO + (size_t)g * 65536;
    const float* xg = x + (size_t)bb * (NNODE * XROW) + (size_t)tt * ND;

    #pragma unroll
    for (int i = 0; i < 4; ++i) {
        int chunk = i * 256 + tid;        // 0..1023
        int n  = chunk >> 4;              // 0..63
        int c4 = (chunk & 15) * 4;        // 0..60
        floatx4 f = *(const floatx4*)(xg + (size_t)(n0 + n) * XROW + c4);
        *(floatx4*)(T + n * 68 + c4) = f;
        bf16x4 h, l;
        #pragma unroll
        for (int j = 0; j < 4; ++j) {
            bfpair p = split1(f[j]); h[j] = p.h; l[j] = p.l;
        }
        *(bf16x4*)(Xhi + (size_t)(n0 + n) * 64 + c4) = h;
        *(bf16x4*)(Xlo + (size_t)(n0 + n) * 64 + c4) = l;
    }
    __syncthreads();

    {   // transposed + permuted split: thread owns (d, 16 consecutive dst pos)
        const int d  = tid >> 2;          // 0..63
        const int nc = (tid & 3) * 16;    // 0..48 (dst positions nc..nc+15)
        const int tb = nc & 32;           // 32-key tile base within the 64-blk
        bf16x8 h0, l0, h1, l1;
        #pragma unroll
        for (int j = 0; j < 8; ++j) {
            int c0 = (nc & 31) + j;       // dst position in tile
            int k0 = ((c0 & 7) >> 2) * 16 + (c0 >> 3) * 4 + (c0 & 3);
            bfpair p = split1(T[(tb + k0) * 68 + d]);
            h0[j] = p.h; l0[j] = p.l;
            int c1 = (nc & 31) + 8 + j;
            int k1 = ((c1 & 7) >> 2) * 16 + (c1 >> 3) * 4 + (c1 & 3);
            bfpair q = split1(T[(tb + k1) * 68 + d]);
            h1[j] = q.h; l1[j] = q.l;
        }
        __bf16* dsth = VPhi + (size_t)d * NNODE + n0 + nc;
        __bf16* dstl = VPlo + (size_t)d * NNODE + n0 + nc;
        *(bf16x8*)dsth = h0; *(bf16x8*)(dsth + 8) = h1;
        *(bf16x8*)dstl = l0; *(bf16x8*)(dstl + 8) = l1;
    }

    if (bx < 2) {                         // theta^T split (tiny)
        int c  = bx * 256 + tid;          // 0..511
        int o  = c >> 3;                  // 0..63
        int d0 = (c & 7) * 8;             // 0..56
        bf16x8 h, l;
        #pragma unroll
        for (int i = 0; i < 8; ++i) {
            bfpair p = split1(theta[(size_t)(d0 + i) * ND + o]);
            h[i] = p.h; l[i] = p.l;
        }
        *(bf16x8*)(ws + WTHI + (size_t)o * 64 + d0) = h;
        *(bf16x8*)(ws + WTLO + (size_t)o * 64 + d0) = l;
    }
}

// ---------------------------------------------------------------------------
// spattn5: grid 768 (bx = rblk*96 + g), 256 threads, 4 waves x 32 rows.
// Swapped QK^T; P in registers; K/V LDS staging as R9.
// ---------------------------------------------------------------------------
__global__ void __launch_bounds__(256, 4)
spattn5(const __bf16* __restrict__ ws, const float* __restrict__ adj,
        float* __restrict__ out)
{
    __shared__ __align__(16) char smem[SMEM5];
    __bf16* Khi = (__bf16*)(smem + OFF_KHI);
    __bf16* Klo = (__bf16*)(smem + OFF_KLO);
    __bf16* Vhi = (__bf16*)(smem + OFF_VHI);
    __bf16* Vlo = (__bf16*)(smem + OFF_VLO);

    const int tid  = threadIdx.x;
    const int wave = tid >> 6;          // 0..3, owns rows wave*32..+31
    const int lane = tid & 63;
    const int l16  = lane & 15;
    const int quad = lane >> 4;

    // bx = rblk*96 + g: all 8 row-blocks of a g share bx%8 -> same XCD.
    const int bx   = blockIdx.x;
    const int g    = bx % NG;           // 0..95
    const int rblk = bx / NG;           // 0..7
    const int bb   = g / NT;
    const int tt   = g - bb * NT;
    const int row0 = rblk * 128;

    const __bf16* xh  = ws + WXHI  + (size_t)g * 65536;
    const __bf16* xl  = ws + WXLO  + (size_t)g * 65536;
    const __bf16* vph = ws + WVPHI + (size_t)g * 65536;
    const __bf16* vpl = ws + WVPLO + (size_t)g * 65536;

    // ---- Q fragments b128 from row-major split arrays (identical to R9;
    //      now used as the MFMA B operand — same lane->element map) ----
    bf16x8 qhi[2][2], qlo[2][2];
    #pragma unroll
    for (int mt = 0; mt < 2; ++mt) {
        const __bf16* q0 = xh + (size_t)(row0 + wave*32 + mt*16 + l16) * 64 + quad*8;
        const __bf16* q1 = xl + (size_t)(row0 + wave*32 + mt*16 + l16) * 64 + quad*8;
        #pragma unroll
        for (int ks = 0; ks < 2; ++ks) {
            qhi[mt][ks] = *(const bf16x8*)(q0 + ks*32);
            qlo[mt][ks] = *(const bf16x8*)(q1 + ks*32);
        }
    }

    const floatx4 vzero = {0.f, 0.f, 0.f, 0.f};
    floatx4 acc[2][4];
    #pragma unroll
    for (int mt = 0; mt < 2; ++mt)
        #pragma unroll
        for (int dt = 0; dt < 4; ++dt)
            acc[mt][dt] = vzero;
    float lpart[2] = {0.f, 0.f};        // per-lane partial: q = l16 (per mt)

    // staging maps (R9 geometry; V from the permuted transposed ws)
    const int skey = tid >> 3;          // 0..31
    const int sd0  = (tid & 7) * 8;     // 0..56
    const int svd  = tid >> 2;          // 0..63
    const int svk0 = (tid & 3) * 8;     // 0..24

    bf16x8 kh, kl, vhs, vls;            // register prefetch (tile 0)
    kh  = *(const bf16x8*)(xh  + (size_t)skey * 64 + sd0);
    kl  = *(const bf16x8*)(xl  + (size_t)skey * 64 + sd0);
    vhs = *(const bf16x8*)(vph + (size_t)svd * NNODE + svk0);
    vls = *(const bf16x8*)(vpl + (size_t)svd * NNODE + svk0);

    for (int ct = 0; ct < 32; ++ct) {
        const int key0 = ct * 32;
        __syncthreads();                       // prior tile's LDS reads done
        *(bf16x8*)(Khi + skey*KSTRIDE + sd0) = kh;
        *(bf16x8*)(Klo + skey*KSTRIDE + sd0) = kl;
        *(bf16x8*)(Vhi + svd*VSTRIDE + svk0) = vhs;
        *(bf16x8*)(Vlo + svd*VSTRIDE + svk0) = vls;
        __syncthreads();                       // staging visible
        if (ct < 31) { // register prefetch of next tile, overlaps compute
            const int nk = key0 + 32;
            kh  = *(const bf16x8*)(xh  + (size_t)(nk + skey) * 64 + sd0);
            kl  = *(const bf16x8*)(xl  + (size_t)(nk + skey) * 64 + sd0);
            vhs = *(const bf16x8*)(vph + (size_t)svd * NNODE + nk + svk0);
            vls = *(const bf16x8*)(vpl + (size_t)svd * NNODE + nk + svk0);
        }
        // adj: float4 loads; lane l16 = q-row, quad*4+r = key within nt-tile
        floatx4 av[2][2];
        #pragma unroll
        for (int mt = 0; mt < 2; ++mt)
            #pragma unroll
            for (int nt = 0; nt < 2; ++nt)
                av[mt][nt] = *(const floatx4*)(adj
                    + (size_t)(row0 + wave*32 + mt*16 + l16) * NNODE
                    + key0 + nt*16 + quad*4);

        // ---- S^T = K Q^T (swapped operands; 3-term split bf16) ----
        // Output: col = q = l16, row = key = nt*16 + quad*4 + r.
        floatx4 S[2][2] = {{vzero, vzero}, {vzero, vzero}};   // [mt][nt]
        #pragma unroll
        for (int ks = 0; ks < 2; ++ks) {
            #pragma unroll
            for (int nt = 0; nt < 2; ++nt) {
                bf16x8 ah = *(const bf16x8*)(Khi + (nt*16 + l16)*KSTRIDE + ks*32 + quad*8);
                bf16x8 al = *(const bf16x8*)(Klo + (nt*16 + l16)*KSTRIDE + ks*32 + quad*8);
                #pragma unroll
                for (int mt = 0; mt < 2; ++mt) {
                    S[mt][nt] = MFMA(ah, qhi[mt][ks], S[mt][nt]);
                    S[mt][nt] = MFMA(ah, qlo[mt][ks], S[mt][nt]);
                    S[mt][nt] = MFMA(al, qhi[mt][ks], S[mt][nt]);
                }
            }
        }

        // ---- exp2 + adj-mask + split, ALL in registers ----
        // P A-frag position j of quad: (nt=j>>2, r=j&3) -> matches the
        // k-permutation baked into the V workspace.
        bf16x8 pah[2], pal[2];
        #pragma unroll
        for (int mt = 0; mt < 2; ++mt)
            #pragma unroll
            for (int nt = 0; nt < 2; ++nt)
                #pragma unroll
                for (int r = 0; r < 4; ++r) {
                    float w = __builtin_amdgcn_exp2f(S[mt][nt][r] * QSCALE);
                    lpart[mt] += w;
                    bfpair pp = split1(av[mt][nt][r] * w);
                    pah[mt][nt*4 + r] = pp.h;
                    pal[mt][nt*4 + r] = pp.l;
                }

        // ---- agg += P . V (3-term split; V B-frags from permuted LDS) ----
        #pragma unroll
        for (int dt = 0; dt < 4; ++dt) {
            bf16x8 vvh = *(const bf16x8*)(Vhi + (dt*16 + l16)*VSTRIDE + quad*8);
            bf16x8 vvl = *(const bf16x8*)(Vlo + (dt*16 + l16)*VSTRIDE + quad*8);
            #pragma unroll
            for (int mt = 0; mt < 2; ++mt) {
                acc[mt][dt] = MFMA(pah[mt], vvh, acc[mt][dt]);
                acc[mt][dt] = MFMA(pal[mt], vvh, acc[mt][dt]);
                acc[mt][dt] = MFMA(pah[mt], vvl, acc[mt][dt]);
            }
        }
    }

    // ---- denominator: reduce across quads (each lane has q = l16) ----
    float linv[2][4];
    #pragma unroll
    for (int mt = 0; mt < 2; ++mt) {
        float lv = lpart[mt];
        lv += __shfl_xor(lv, 16);
        lv += __shfl_xor(lv, 32);           // lanes 0..15 hold full sums
        #pragma unroll
        for (int r = 0; r < 4; ++r)
            linv[mt][r] = 1.0f / __shfl(lv, quad*4 + r);
    }

    // ---- epilogue: out = relu((agg/l) @ theta), split-bf16 MFMA ----
    __syncthreads();                       // everyone done with K/V LDS
    float* AG = (float*)smem;              // [128][AGSTRIDE] overlay
    #pragma unroll
    for (int mt = 0; mt < 2; ++mt)
        #pragma unroll
        for (int dt = 0; dt < 4; ++dt)
            #pragma unroll
            for (int r = 0; r < 4; ++r)
                AG[(wave*32 + mt*16 + quad*4 + r)*AGSTRIDE + dt*16 + l16]
                    = acc[mt][dt][r] * linv[mt][r];

    const __bf16* Th = ws + WTHI;
    const __bf16* Tl = ws + WTLO;
    bf16x8 th[4][2], tlw[4][2];
    #pragma unroll
    for (int ot = 0; ot < 4; ++ot)
        #pragma unroll
        for (int ks = 0; ks < 2; ++ks) {
            th[ot][ks]  = *(const bf16x8*)(Th + (size_t)(ot*16 + l16)*64 + ks*32 + quad*8);
            tlw[ot][ks] = *(const bf16x8*)(Tl + (size_t)(ot*16 + l16)*64 + ks*32 + quad*8);
        }

    floatx4 oacc[2][4];
    #pragma unroll
    for (int mt = 0; mt < 2; ++mt)
        #pragma unroll
        for (int ot = 0; ot < 4; ++ot)
            oacc[mt][ot] = vzero;
    __syncthreads();                       // AG region fully written
    #pragma unroll
    for (int ks = 0; ks < 2; ++ks) {
        bf16x8 ah[2], al[2];
        #pragma unroll
        for (int mt = 0; mt < 2; ++mt) {
            const float* ap = AG + (wave*32 + mt*16 + l16)*AGSTRIDE + ks*32 + quad*8;
            floatx4 a0 = *(const floatx4*)ap;
            floatx4 a1 = *(const floatx4*)(ap + 4);
            #pragma unroll
            for (int i = 0; i < 4; ++i) {
                bfpair q0 = split1(a0[i]); ah[mt][i]   = q0.h; al[mt][i]   = q0.l;
                bfpair q1 = split1(a1[i]); ah[mt][4+i] = q1.h; al[mt][4+i] = q1.l;
            }
        }
        #pragma unroll
        for (int ot = 0; ot < 4; ++ot)
            #pragma unroll
            for (int mt = 0; mt < 2; ++mt) {
                oacc[mt][ot] = MFMA(ah[mt], th[ot][ks], oacc[mt][ot]);
                oacc[mt][ot] = MFMA(al[mt], th[ot][ks], oacc[mt][ot]);
                oacc[mt][ot] = MFMA(ah[mt], tlw[ot][ks], oacc[mt][ot]);
            }
    }

    float* obase = out + (size_t)bb * (NNODE * XROW) + tt * ND;
    #pragma unroll
    for (int mt = 0; mt < 2; ++mt)
        #pragma unroll
        for (int ot = 0; ot < 4; ++ot)
            #pragma unroll
            for (int r = 0; r < 4; ++r) {
                float v = oacc[mt][ot][r];
                obase[(size_t)(row0 + wave*32 + mt*16 + quad*4 + r) * XROW + ot*16 + l16]
                    = v > 0.f ? v : 0.f;
            }
}

// ---------------------------------------------------------------------------
// Fallback: verified R5 kernel (used only if workspace is too small).
// ---------------------------------------------------------------------------
__global__ void __launch_bounds__(256, 2)
spattn_fb(const float* __restrict__ x, const float* __restrict__ adj,
          const float* __restrict__ theta, float* __restrict__ out)
{
    __shared__ __align__(16) char smem[SMEM_FB];
    __bf16* Khi = (__bf16*)(smem + OFF_KHI);
    __bf16* Klo = (__bf16*)(smem + OFF_KLO);
    __bf16* Vhi = (__bf16*)(smem + OFF_VHI);
    __bf16* Vlo = (__bf16*)(smem + OFF_VLO);
    float*  Pm  = (float*)(smem + OFF_P);

    const int tid  = threadIdx.x;
    const int wave = tid >> 6;
    const int lane = tid & 63;
    const int l16  = lane & 15;
    const int quad = lane >> 4;

    const int bx   = blockIdx.x;
    const int g    = bx >> 3;
    const int rblk = bx & 7;
    const int bb   = g / NT;
    const int tt   = g - bb * NT;
    const int row0 = rblk * 128;

    const float* xbase = x + (size_t)bb * (NNODE * XROW) + tt * ND;

    bf16x8 qhi[2][2], qlo[2][2];
    #pragma unroll
    for (int mt = 0; mt < 2; ++mt) {
        const float* qsrc = xbase + (size_t)(row0 + wave*32 + mt*16 + l16) * XROW;
        #pragma unroll
        for (int ks = 0; ks < 2; ++ks) {
            floatx4 f0 = *(const floatx4*)(qsrc + ks*32 + quad*8);
            floatx4 f1 = *(const floatx4*)(qsrc + ks*32 + quad*8 + 4);
            #pragma unroll
            for (int i = 0; i < 4; ++i) {
                bfpair p0 = split1(f0[i]*QSCALE);
                qhi[mt][ks][i]   = p0.h; qlo[mt][ks][i]   = p0.l;
                bfpair p1 = split1(f1[i]*QSCALE);
                qhi[mt][ks][4+i] = p1.h; qlo[mt][ks][4+i] = p1.l;
            }
        }
    }

    const floatx4 vzero = {0.f, 0.f, 0.f, 0.f};
    floatx4 acc[2][4];
    #pragma unroll
    for (int mt = 0; mt < 2; ++mt)
        #pragma unroll
        for (int dt = 0; dt < 4; ++dt)
            acc[mt][dt] = vzero;
    float lpart[2][4] = {{0.f,0.f,0.f,0.f},{0.f,0.f,0.f,0.f}};

    const int skey = tid >> 3;
    const int sd0  = (tid & 7) * 8;
    const int svd  = tid >> 2;
    const int svk0 = (tid & 3) * 8;
    floatx4 kf0, kf1;
    float vf[8];

    {
        const float* ksrc = xbase + (size_t)skey * XROW + sd0;
        kf0 = *(const floatx4*)ksrc;
        kf1 = *(const floatx4*)(ksrc + 4);
        const float* vsrc = xbase + (size_t)svk0 * XROW + svd;
        #pragma unroll
        for (int i = 0; i < 8; ++i) vf[i] = vsrc[i * XROW];
    }

    for (int ct = 0; ct < 32; ++ct) {
        const int key0 = ct * 32;
        __syncthreads();
        {
            bf16x8 h, l;
            #pragma unroll
            for (int i = 0; i < 4; ++i) {
                bfpair p0 = split1(kf0[i]); h[i]   = p0.h; l[i]   = p0.l;
                bfpair p1 = split1(kf1[i]); h[4+i] = p1.h; l[4+i] = p1.l;
            }
            *(bf16x8*)(Khi + skey*KSTRIDE + sd0) = h;
            *(bf16x8*)(Klo + skey*KSTRIDE + sd0) = l;
            bf16x8 vh, vl;
            #pragma unroll
            for (int i = 0; i < 8; ++i) {
                bfpair p = split1(vf[i]); vh[i] = p.h; vl[i] = p.l;
            }
            *(bf16x8*)(Vhi + svd*VSTRIDE + svk0) = vh;
            *(bf16x8*)(Vlo + svd*VSTRIDE + svk0) = vl;
        }
        __syncthreads();
        if (ct < 31) {
            const int nk = key0 + 32;
            const float* ksrc = xbase + (size_t)(nk + skey) * XROW + sd0;
            kf0 = *(const floatx4*)ksrc;
            kf1 = *(const floatx4*)(ksrc + 4);
            const float* vsrc = xbase + (size_t)(nk + svk0) * XROW + svd;
            #pragma unroll
            for (int i = 0; i < 8; ++i) vf[i] = vsrc[i * XROW];
        }
        float av[2][2][4];
        #pragma unroll
        for (int mt = 0; mt < 2; ++mt)
            #pragma unroll
            for (int nt = 0; nt < 2; ++nt)
                #pragma unroll
                for (int r = 0; r < 4; ++r)
                    av[mt][nt][r] = adj[(size_t)(row0 + wave*32 + mt*16 + quad*4 + r) * NNODE
                                        + key0 + nt*16 + l16];

        floatx4 S[2][2] = {{vzero, vzero}, {vzero, vzero}};
        #pragma unroll
        for (int ks = 0; ks < 2; ++ks) {
            #pragma unroll
            for (int nt = 0; nt < 2; ++nt) {
                bf16x8 bh = *(const bf16x8*)(Khi + (nt*16 + l16)*KSTRIDE + ks*32 + quad*8);
                bf16x8 bl = *(const bf16x8*)(Klo + (nt*16 + l16)*KSTRIDE + ks*32 + quad*8);
                #pragma unroll
                for (int mt = 0; mt < 2; ++mt) {
                    S[mt][nt] = MFMA(qhi[mt][ks], bh, S[mt][nt]);
                    S[mt][nt] = MFMA(qlo[mt][ks], bh, S[mt][nt]);
                    S[mt][nt] = MFMA(qhi[mt][ks], bl, S[mt][nt]);
                }
            }
        }
        #pragma unroll
        for (int mt = 0; mt < 2; ++mt)
            #pragma unroll
            for (int nt = 0; nt < 2; ++nt)
                #pragma unroll
                for (int r = 0; r < 4; ++r) {
                    float w = __builtin_amdgcn_exp2f(S[mt][nt][r]);
                    lpart[mt][r] += w;
                    Pm[(wave*32 + mt*16 + quad*4 + r)*PSTRIDE + nt*16 + l16] = av[mt][nt][r] * w;
                }
        bf16x8 pah[2], pal[2];
        #pragma unroll
        for (int mt = 0; mt < 2; ++mt) {
            const float* pp = Pm + (wave*32 + mt*16 + l16)*PSTRIDE + quad*8;
            floatx4 p0 = *(const floatx4*)pp;
            floatx4 p1 = *(const floatx4*)(pp + 4);
            #pragma unroll
            for (int i = 0; i < 4; ++i) {
                bfpair q0 = split1(p0[i]); pah[mt][i]   = q0.h; pal[mt][i]   = q0.l;
                bfpair q1 = split1(p1[i]); pah[mt][4+i] = q1.h; pal[mt][4+i] = q1.l;
            }
        }
        #pragma unroll
        for (int dt = 0; dt < 4; ++dt) {
            bf16x8 vh = *(const bf16x8*)(Vhi + (dt*16 + l16)*VSTRIDE + quad*8);
            bf16x8 vl = *(const bf16x8*)(Vlo + (dt*16 + l16)*VSTRIDE + quad*8);
            #pragma unroll
            for (int mt = 0; mt < 2; ++mt) {
                acc[mt][dt] = MFMA(pah[mt], vh, acc[mt][dt]);
                acc[mt][dt] = MFMA(pal[mt], vh, acc[mt][dt]);
                acc[mt][dt] = MFMA(pah[mt], vl, acc[mt][dt]);
            }
        }
    }

    float linv[2][4];
    #pragma unroll
    for (int mt = 0; mt < 2; ++mt)
        #pragma unroll
        for (int r = 0; r < 4; ++r) {
            float lv = lpart[mt][r];
            lv += __shfl_xor(lv, 1);
            lv += __shfl_xor(lv, 2);
            lv += __shfl_xor(lv, 4);
            lv += __shfl_xor(lv, 8);
            linv[mt][r] = 1.0f / lv;
        }

    __syncthreads();
    float* AG = (float*)smem;
    #pragma unroll
    for (int mt = 0; mt < 2; ++mt)
        #pragma unroll
        for (int dt = 0; dt < 4; ++dt)
            #pragma unroll
            for (int r = 0; r < 4; ++r)
                AG[(wave*32 + mt*16 + quad*4 + r)*AGSTRIDE + dt*16 + l16]
                    = acc[mt][dt][r] * linv[mt][r];

    bf16x8 th[4][2], tl[4][2];
    #pragma unroll
    for (int ot = 0; ot < 4; ++ot)
        #pragma unroll
        for (int ks = 0; ks < 2; ++ks)
            #pragma unroll
            for (int j = 0; j < 8; ++j) {
                float tv = theta[(ks*32 + quad*8 + j)*ND + ot*16 + l16];
                bfpair p = split1(tv);
                th[ot][ks][j] = p.h; tl[ot][ks][j] = p.l;
            }

    floatx4 oacc[2][4];
    #pragma unroll
    for (int mt = 0; mt < 2; ++mt)
        #pragma unroll
        for (int ot = 0; ot < 4; ++ot)
            oacc[mt][ot] = vzero;
    __syncthreads();
    #pragma unroll
    for (int ks = 0; ks < 2; ++ks) {
        bf16x8 ah[2], al[2];
        #pragma unroll
        for (int mt = 0; mt < 2; ++mt) {
            const float* ap = AG + (wave*32 + mt*16 + l16)*AGSTRIDE + ks*32 + quad*8;
            floatx4 a0 = *(const floatx4*)ap;
            floatx4 a1 = *(const floatx4*)(ap + 4);
            #pragma unroll
            for (int i = 0; i < 4; ++i) {
                bfpair q0 = split1(a0[i]); ah[mt][i]   = q0.h; al[mt][i]   = q0.l;
                bfpair q1 = split1(a1[i]); ah[mt][4+i] = q1.h; al[mt][4+i] = q1.l;
            }
        }
        #pragma unroll
        for (int ot = 0; ot < 4; ++ot)
            #pragma unroll
            for (int mt = 0; mt < 2; ++mt) {
                oacc[mt][ot] = MFMA(ah[mt], th[ot][ks], oacc[mt][ot]);
                oacc[mt][ot] = MFMA(al[mt], th[ot][ks], oacc[mt][ot]);
                oacc[mt][ot] = MFMA(ah[mt], tl[ot][ks], oacc[mt][ot]);
            }
    }

    float* obase = out + (size_t)bb * (NNODE * XROW) + tt * ND;
    #pragma unroll
    for (int mt = 0; mt < 2; ++mt)
        #pragma unroll
        for (int ot = 0; ot < 4; ++ot)
            #pragma unroll
            for (int r = 0; r < 4; ++r) {
                float v = oacc[mt][ot][r];
                obase[(size_t)(row0 + wave*32 + mt*16 + quad*4 + r) * XROW + ot*16 + l16]
                    = v > 0.f ? v : 0.f;
            }
}

extern "C" void kernel_launch(void* const* d_in, const int* in_sizes, int n_in,
                              void* d_out, int out_size, void* d_ws, size_t ws_size,
                              hipStream_t stream) {
    (void)in_sizes; (void)n_in; (void)out_size;
    const float* x     = (const float*)d_in[0];
    const float* adj   = (const float*)d_in[1];
    const float* theta = (const float*)d_in[2];
    float* out = (float*)d_out;
    if (d_ws != nullptr && ws_size >= WS_BYTES) {
        __bf16* ws = (__bf16*)d_ws;
        presplit<<<dim3(1536), dim3(256), 0, stream>>>(x, theta, ws);
        spattn5<<<dim3(768), dim3(256), 0, stream>>>(ws, adj, out);
    } else {
        spattn_fb<<<dim3(768), dim3(256), 0, stream>>>(x, adj, theta, out);
    }
}